// Round 10
// baseline (343.013 us; speedup 1.0000x reference)
//
#include <hip/hip_runtime.h>
#include <string.h>

// Problem constants: B=2, obj=4, C=256, H=W=48, N=8, HW=2304
#define HH 48
#define WW 48
#define HWP 2304
#define CC 256
#define NB 8
#define QKROW 2305   // 2304 rows + 1 zero pad row (index 2304) for OOB taps

typedef __attribute__((ext_vector_type(8))) short short8;   // 8 x bf16 = 4 VGPR
typedef __attribute__((ext_vector_type(4))) float floatx4;  // MFMA C/D frag

static __device__ __forceinline__ unsigned short f2bf(float f) {
    union { float f; unsigned u; } v; v.f = f;
    unsigned r = v.u + 0x7fffu + ((v.u >> 16) & 1u);        // RNE
    return (unsigned short)(r >> 16);
}
static __device__ __forceinline__ float bflo(unsigned u) {
    union { unsigned u; float f; } x; x.u = u << 16; return x.f;
}
static __device__ __forceinline__ float bfhi(unsigned u) {
    union { unsigned u; float f; } x; x.u = u & 0xffff0000u; return x.f;
}
static __device__ __forceinline__ unsigned fbits(float f) {
    union { float f; unsigned u; } x; x.f = f; return x.u;
}

// ---- tiled transpose q/k -> qkT[b][px][c2] bf16 (64x64 tiles via LDS) ------
__global__ __launch_bounds__(256) void k_tr_qk(const float* __restrict__ q,
        const float* __restrict__ kk, unsigned short* __restrict__ qkT) {
    __shared__ float T[64][65];
    const int pg = blockIdx.x, cg = blockIdx.y;
    const int b = blockIdx.z >> 1, src = blockIdx.z & 1;
    const float* s = (src ? kk : q) + (size_t)b * CC * HWP;
    const int tx = threadIdx.x & 63, ty = threadIdx.x >> 6;
#pragma unroll
    for (int i = 0; i < 16; i++) {
        int cl = ty * 16 + i;
        T[cl][tx] = s[(size_t)(cg * 64 + cl) * HWP + pg * 64 + tx];
    }
    __syncthreads();
#pragma unroll
    for (int i = 0; i < 16; i++) {
        int pxl = ty * 16 + i;
        qkT[((size_t)b * QKROW + pg * 64 + pxl) * 512 + src * 256 + cg * 64 + tx]
            = f2bf(T[tx][pxl]);
    }
}

// ---- tiled transpose value -> vT[n][px][c] bf16 ----------------------------
__global__ __launch_bounds__(256) void k_tr_v(const float* __restrict__ v,
                                              unsigned short* __restrict__ vT) {
    __shared__ float T[64][65];
    const int pg = blockIdx.x, cg = blockIdx.y, n = blockIdx.z;
    const float* s = v + (size_t)n * CC * HWP;
    const int tx = threadIdx.x & 63, ty = threadIdx.x >> 6;
#pragma unroll
    for (int i = 0; i < 16; i++) {
        int cl = ty * 16 + i;
        T[cl][tx] = s[(size_t)(cg * 64 + cl) * HWP + pg * 64 + tx];
    }
    __syncthreads();
#pragma unroll
    for (int i = 0; i < 16; i++) {
        int pxl = ty * 16 + i;
        vT[((size_t)n * HWP + pg * 64 + pxl) * 256 + cg * 64 + tx] = f2bf(T[tx][pxl]);
    }
}

// ---- weight preshuffle into MFMA-fragment order (1KB contiguous frags) -----
__global__ __launch_bounds__(256) void k_prep_w(const float* __restrict__ w1,
        const float* __restrict__ dw, const float* __restrict__ w2,
        unsigned short* __restrict__ w1r, unsigned short* __restrict__ wdr,
        unsigned short* __restrict__ w2r) {
    int idx = blockIdx.x * 256 + threadIdx.x;
    if (idx < 1179648) {
        int j = idx & 7, l = (idx >> 3) & 63, mtg = (idx >> 9) & 15;
        int kk = (idx >> 13) & 15, tap = idx >> 17;
        int o = mtg * 16 + (l & 15);
        int c2 = kk * 32 + (l >> 4) * 8 + j;
        w1r[idx] = f2bf(w1[((size_t)o * 512 + c2) * 9 + tap]);
    } else if (idx < 1179648 + 589824) {
        int i2 = idx - 1179648;
        int j = i2 & 7, l = (i2 >> 3) & 63, mtg = (i2 >> 9) & 15;
        int kk = (i2 >> 13) & 7, tap = i2 >> 16;
        int o = mtg * 16 + (l & 15);
        int c = kk * 32 + (l >> 4) * 8 + j;
        wdr[i2] = f2bf(dw[((size_t)o * 256 + c) * 9 + tap]);
    } else {
        int i2 = idx - 1179648 - 589824;
        int j = i2 & 7, l = (i2 >> 3) & 63, mt = (i2 >> 9) & 1;
        int kk = (i2 >> 10) & 7, tap = i2 >> 13;
        int o = mt * 16 + (l & 15);
        int c = kk * 32 + (l >> 4) * 8 + j;
        w2r[i2] = (o < 18) ? f2bf(w2[((size_t)o * 256 + c) * 9 + tap]) : 0;
    }
}

// ---- zero qkT pad rows ------------------------------------------------------
__global__ __launch_bounds__(256) void k_pads(unsigned short* __restrict__ qkT) {
    int t = threadIdx.x;
#pragma unroll
    for (int b = 0; b < 2; b++) {
        qkT[((size_t)b * QKROW + HWP) * 512 + t] = 0;
        qkT[((size_t)b * QKROW + HWP) * 512 + 256 + t] = 0;
    }
}

// ---- conv1: tap-split(3) MFMA GEMM -> fp32 partials feat3[g][b][px][o] -----
__global__ __launch_bounds__(256) void k_conv1(const unsigned short* __restrict__ qkT,
        const unsigned short* __restrict__ w1r, float* __restrict__ feat3) {
    const int tid = threadIdx.x;
    const int pb = blockIdx.x;            // 144
    const int b  = blockIdx.y;
    const int g  = blockIdx.z;            // tap row (dy = g-1)
    const int lane = tid & 63, wv = tid >> 6;
    const int lo = lane & 15, quad = lane >> 4;
    const int pp = pb * 16 + lo;
    const int h = pp / WW, w = pp - (pp / WW) * WW;

    floatx4 acc[4];
#pragma unroll
    for (int mt = 0; mt < 4; mt++) acc[mt] = (floatx4)0.f;

#pragma unroll
    for (int t3 = 0; t3 < 3; t3++) {
        const int tap = g * 3 + t3;
        const int dy = g - 1, dx = t3 - 1;
        const bool val = (h + dy >= 0) && (h + dy < HH) && (w + dx >= 0) && (w + dx < WW);
        const int row = val ? (pp + dy * WW + dx) : HWP;
        const unsigned short* brow = qkT + ((size_t)b * QKROW + row) * 512 + quad * 8;
        const unsigned short* afr = w1r + (((size_t)tap * 16 * 16 + wv * 4) * 64 + lane) * 8;
#pragma unroll 4
        for (int ks = 0; ks < 16; ks++) {
            short8 bf = *(const short8*)(brow + ks * 32);
            const unsigned short* ak = afr + (size_t)ks * 16 * 512;
            short8 a0 = *(const short8*)(ak);
            short8 a1 = *(const short8*)(ak + 512);
            short8 a2 = *(const short8*)(ak + 1024);
            short8 a3 = *(const short8*)(ak + 1536);
            acc[0] = __builtin_amdgcn_mfma_f32_16x16x32_bf16(a0, bf, acc[0], 0, 0, 0);
            acc[1] = __builtin_amdgcn_mfma_f32_16x16x32_bf16(a1, bf, acc[1], 0, 0, 0);
            acc[2] = __builtin_amdgcn_mfma_f32_16x16x32_bf16(a2, bf, acc[2], 0, 0, 0);
            acc[3] = __builtin_amdgcn_mfma_f32_16x16x32_bf16(a3, bf, acc[3], 0, 0, 0);
        }
    }

    float* dst = feat3 + (((size_t)g * 2 + b) * HWP + pp) * 256;
#pragma unroll
    for (int mt = 0; mt < 4; mt++) {
        int o = wv * 64 + mt * 16 + quad * 4;
        *(floatx4*)(dst + o) = acc[mt];
    }
}

// ---- fcast: featb[b][px][o] = bf16(sum_g feat3 + b1), pad row zero ---------
__global__ __launch_bounds__(256) void k_fcast(const float* __restrict__ feat3,
        const float* __restrict__ b1, unsigned short* __restrict__ featb) {
    const int row = blockIdx.x;           // 0..2304
    const int b = blockIdx.y;
    const int c = threadIdx.x;
    size_t oidx = ((size_t)b * QKROW + row) * 256 + c;
    if (row < HWP) {
        float s = feat3[(((size_t)0 * 2 + b) * HWP + row) * 256 + c]
                + feat3[(((size_t)1 * 2 + b) * HWP + row) * 256 + c]
                + feat3[(((size_t)2 * 2 + b) * HWP + row) * 256 + c] + b1[c];
        featb[oidx] = f2bf(s);
    } else {
        featb[oidx] = 0;
    }
}

// ---- conv2: tap-split(9) -> fp32 partials off9[t][b][px][32] ---------------
__global__ __launch_bounds__(256) void k_conv2(const unsigned short* __restrict__ featb,
        const unsigned short* __restrict__ w2r, float* __restrict__ off9) {
    const int tid = threadIdx.x;
    const int pb = blockIdx.x;            // 36
    const int b  = blockIdx.y;
    const int tap = blockIdx.z;
    const int lane = tid & 63, wv = tid >> 6;
    const int lo = lane & 15, quad = lane >> 4;
    const int pp = pb * 64 + wv * 16 + lo;
    const int h = pp / WW, w = pp - (pp / WW) * WW;
    const int dy = tap / 3 - 1, dx = tap % 3 - 1;
    const bool val = (h + dy >= 0) && (h + dy < HH) && (w + dx >= 0) && (w + dx < WW);
    const int row = val ? (pp + dy * WW + dx) : HWP;

    const unsigned short* brow = featb + ((size_t)b * QKROW + row) * 256 + quad * 8;
    const unsigned short* afr = w2r + (((size_t)tap * 8 * 2) * 64 + lane) * 8;

    floatx4 acc[2];
    acc[0] = (floatx4)0.f; acc[1] = (floatx4)0.f;
#pragma unroll
    for (int ks = 0; ks < 8; ks++) {
        short8 bf = *(const short8*)(brow + ks * 32);
        const unsigned short* ak = afr + (size_t)ks * 2 * 512;
        short8 a0 = *(const short8*)(ak);
        short8 a1 = *(const short8*)(ak + 512);
        acc[0] = __builtin_amdgcn_mfma_f32_16x16x32_bf16(a0, bf, acc[0], 0, 0, 0);
        acc[1] = __builtin_amdgcn_mfma_f32_16x16x32_bf16(a1, bf, acc[1], 0, 0, 0);
    }

    float* dst = off9 + (((size_t)tap * 2 + b) * HWP + pp) * 32;
#pragma unroll
    for (int mt = 0; mt < 2; mt++) {
        int o = mt * 16 + quad * 4;
        *(floatx4*)(dst + o) = acc[mt];
    }
}

// ---- osum: off[b][o][px] = sum_t off9 + b2[o]  (o<18) ----------------------
__global__ __launch_bounds__(256) void k_osum(const float* __restrict__ off9,
        const float* __restrict__ b2, float* __restrict__ off) {
    int i = blockIdx.x * 256 + threadIdx.x;        // < 2*18*2304
    int b = i / (18 * HWP);
    int r = i - b * 18 * HWP;
    int o = r / HWP, px = r - o * HWP;
    float s = b2[o];
#pragma unroll
    for (int t = 0; t < 9; t++)
        s += off9[(((size_t)t * 2 + b) * HWP + px) * 32 + o];
    off[i] = s;
}

// ---- deform body: taps [TAP0, TAP0+NT), wave-per-pixel staging -------------
// Block = 64 px. Staging: wave wv stages px [wv*16, wv*16+16): per pixel, the
// whole wave loads each 512B corner row contiguously (8B/lane, 8 lines/instr),
// weights wave-uniform (scalarized). GEMM: 4 waves x (64o x 64px), acc 4x4.
template<int TAP0, int NT, bool EPI>
__device__ __forceinline__ void deform_body(unsigned short* Sl,
        const unsigned short* __restrict__ vTn, const float* __restrict__ off,
        const unsigned short* __restrict__ wdr, const float* __restrict__ db,
        const float* __restrict__ q, float* __restrict__ dst,
        int b, int pb, int n, int tid) {
    const int lane = tid & 63, wv = tid >> 6;
    const int lo = lane & 15, quad = lane >> 4;

    floatx4 acc[4][4];
#pragma unroll
    for (int mt = 0; mt < 4; mt++)
#pragma unroll
        for (int nt = 0; nt < 4; nt++) acc[mt][nt] = (floatx4)0.f;

#pragma unroll
    for (int i = 0; i < NT; i++) {
        const int tap = TAP0 + i;

        // ---- stage 16 pixels, wave-per-pixel ----
#pragma unroll 4
        for (int j = 0; j < 16; j++) {
            const int pxl = wv * 16 + j;
            const int pp = pb * 64 + pxl;
            const int h = pp / WW, w = pp - (pp / WW) * WW;
            float dy = off[((size_t)b * 18 + 2 * tap) * HWP + pp];
            float dx = off[((size_t)b * 18 + 2 * tap + 1) * HWP + pp];
            float py = dy + (float)h + (float)(tap / 3 - 1);
            float px = dx + (float)w + (float)(tap % 3 - 1);
            float y0f = floorf(py), x0f = floorf(px);
            int y0 = (int)y0f, x0 = (int)x0f;
            float fy = py - y0f, fx = px - x0f;
            bool y0ok = (y0 >= 0) & (y0 < HH), y1ok = (y0 >= -1) & (y0 < HH - 1);
            bool x0ok = (x0 >= 0) & (x0 < WW), x1ok = (x0 >= -1) & (x0 < WW - 1);
            int y0c = min(max(y0, 0), HH - 1), y1c = min(max(y0 + 1, 0), HH - 1);
            int x0c = min(max(x0, 0), WW - 1), x1c = min(max(x0 + 1, 0), WW - 1);
            float w0 = (y0ok && x0ok) ? (1.f - fy) * (1.f - fx) : 0.f;
            float w1 = (y0ok && x1ok) ? (1.f - fy) * fx         : 0.f;
            float w2 = (y1ok && x0ok) ? fy * (1.f - fx)         : 0.f;
            float w3 = (y1ok && x1ok) ? fy * fx                 : 0.f;
            // whole wave loads this pixel's 4 corner rows contiguously
            uint2 c0 = *(const uint2*)(vTn + (size_t)(y0c * WW + x0c) * 256 + lane * 4);
            uint2 c1 = *(const uint2*)(vTn + (size_t)(y0c * WW + x1c) * 256 + lane * 4);
            uint2 c2 = *(const uint2*)(vTn + (size_t)(y1c * WW + x0c) * 256 + lane * 4);
            uint2 c3 = *(const uint2*)(vTn + (size_t)(y1c * WW + x1c) * 256 + lane * 4);
            uint2 od;
            {
                float slo = w0 * bflo(c0.x) + w1 * bflo(c1.x) + w2 * bflo(c2.x) + w3 * bflo(c3.x);
                float shi = w0 * bfhi(c0.x) + w1 * bfhi(c1.x) + w2 * bfhi(c2.x) + w3 * bfhi(c3.x);
                od.x = __builtin_amdgcn_perm(fbits(shi) + 0x8000u, fbits(slo) + 0x8000u, 0x07060302);
                slo = w0 * bflo(c0.y) + w1 * bflo(c1.y) + w2 * bflo(c2.y) + w3 * bflo(c3.y);
                shi = w0 * bfhi(c0.y) + w1 * bfhi(c1.y) + w2 * bfhi(c2.y) + w3 * bfhi(c3.y);
                od.y = __builtin_amdgcn_perm(fbits(shi) + 0x8000u, fbits(slo) + 0x8000u, 0x07060302);
            }
            // lane covers c in [lane*4, lane*4+4): granule g = lane>>1, half = lane&1
            int phys = (lane >> 1) ^ (pxl & 7);           // XOR-swizzled 16B granules
            *(uint2*)(Sl + pxl * 256 + phys * 8 + (lane & 1) * 4) = od;
        }
        __syncthreads();

        // ---- GEMM over this tap (K=256) ----
        const unsigned short* afr = wdr + (((size_t)tap * 8 * 16 + wv * 4) * 64 + lane) * 8;
#pragma unroll
        for (int ks = 0; ks < 8; ks++) {
            const unsigned short* ak = afr + (size_t)ks * 16 * 512;
            short8 a0 = *(const short8*)(ak);
            short8 a1 = *(const short8*)(ak + 512);
            short8 a2 = *(const short8*)(ak + 1024);
            short8 a3 = *(const short8*)(ak + 1536);
            short8 bf[4];
#pragma unroll
            for (int nt = 0; nt < 4; nt++) {
                int rw = nt * 16 + lo;
                int gr = (ks * 4 + quad) ^ (rw & 7);
                bf[nt] = *(const short8*)(Sl + rw * 256 + gr * 8);
            }
#pragma unroll
            for (int nt = 0; nt < 4; nt++) {
                acc[0][nt] = __builtin_amdgcn_mfma_f32_16x16x32_bf16(a0, bf[nt], acc[0][nt], 0, 0, 0);
                acc[1][nt] = __builtin_amdgcn_mfma_f32_16x16x32_bf16(a1, bf[nt], acc[1][nt], 0, 0, 0);
                acc[2][nt] = __builtin_amdgcn_mfma_f32_16x16x32_bf16(a2, bf[nt], acc[2][nt], 0, 0, 0);
                acc[3][nt] = __builtin_amdgcn_mfma_f32_16x16x32_bf16(a3, bf[nt], acc[3][nt], 0, 0, 0);
            }
        }
        __syncthreads();
    }

    // epilogue
#pragma unroll
    for (int mt = 0; mt < 4; mt++) {
        int o = wv * 64 + mt * 16 + quad * 4;
#pragma unroll
        for (int nt = 0; nt < 4; nt++) {
            int pq = pb * 64 + nt * 16 + lo;
            floatx4 r = acc[mt][nt];
            if (EPI) {
                r[0] += db[o]     + q[((size_t)b * CC + o + 0) * HWP + pq];
                r[1] += db[o + 1] + q[((size_t)b * CC + o + 1) * HWP + pq];
                r[2] += db[o + 2] + q[((size_t)b * CC + o + 2) * HWP + pq];
                r[3] += db[o + 3] + q[((size_t)b * CC + o + 3) * HWP + pq];
            }
            *(floatx4*)(dst + ((size_t)pq * NB + n) * CC + o) = r;
        }
    }
}

// ---- deform: 64px blocks, 2-way tap split in one launch, XCD-swizzled ------
// grid 576: n = bid&7, r = bid>>3 (72): pb = r%36, g = r/36.
// g0: taps 0-3 + (q+db) epilogue -> out ; g1: taps 4-8 -> p1 (k_dsum adds).
__global__ __launch_bounds__(256) void k_deform(const unsigned short* __restrict__ vT,
        const float* __restrict__ off, const unsigned short* __restrict__ wdr,
        const float* __restrict__ db, const float* __restrict__ q,
        float* __restrict__ out, float* __restrict__ p1) {
    __shared__ __align__(16) unsigned short Sl[64 * 256];   // 32 KB

    const int tid = threadIdx.x;
    const int bid = blockIdx.x;           // 576
    const int n   = bid & 7;              // XCD swizzle: same n -> same XCD
    const int r   = bid >> 3;             // 72
    const int pb  = r % 36;
    const int g   = r / 36;               // 0 or 1
    const int b   = n >> 2;
    const unsigned short* vTn = vT + (size_t)n * HWP * 256;

    if (g == 0)
        deform_body<0, 4, true >(Sl, vTn, off, wdr, db, q, out, b, pb, n, tid);
    else
        deform_body<4, 5, false>(Sl, vTn, off, wdr, db, q, p1,  b, pb, n, tid);
}

// ---- dsum: out += p1 (coalesced float4) ------------------------------------
__global__ __launch_bounds__(256) void k_dsum(float* __restrict__ out,
                                              const float* __restrict__ p1) {
    int i = blockIdx.x * 256 + threadIdx.x;        // 1,179,648 float4s
    float4 a = ((const float4*)out)[i];
    float4 c = ((const float4*)p1)[i];
    a.x += c.x; a.y += c.y; a.z += c.z; a.w += c.w;
    ((float4*)out)[i] = a;
}

extern "C" void kernel_launch(void* const* d_in, const int* in_sizes, int n_in,
                              void* d_out, int out_size, void* d_ws, size_t ws_size,
                              hipStream_t stream) {
    const float* q  = (const float*)d_in[0];
    const float* k  = (const float*)d_in[1];
    const float* v  = (const float*)d_in[2];
    const float* w1 = (const float*)d_in[3];
    const float* b1 = (const float*)d_in[4];
    const float* w2 = (const float*)d_in[5];
    const float* b2 = (const float*)d_in[6];
    const float* dw = (const float*)d_in[7];
    const float* db = (const float*)d_in[8];
    float* out = (float*)d_out;

    // ws (~59 MB): off | feat3 | off9 | p1 (fp32) || qkT | vT | featb | w1r | wdr | w2r (bf16)
    float* off   = (float*)d_ws;                          //    82,944 f
    float* feat3 = off + 82944;                           // 3,538,944 f
    float* off9  = feat3 + 3538944;                       // 1,327,104 f
    float* p1    = off9 + 1327104;                        // 4,718,592 f
    unsigned short* qkT   = (unsigned short*)(p1 + 4718592);
    unsigned short* vT    = qkT + 2360320;                // 2*2305*512
    unsigned short* featb = vT + 4718592;                 // 8*2304*256
    unsigned short* w1r   = featb + 1180160;              // 2*2305*256
    unsigned short* wdr   = w1r + 1179648;                // 256*4608 (frag order)
    unsigned short* w2r   = wdr + 589824;                 // 256*2304 (frag order)

    hipLaunchKernelGGL(k_tr_qk, dim3(36, 4, 4),  dim3(256), 0, stream, q, k, qkT);
    hipLaunchKernelGGL(k_tr_v,  dim3(36, 4, 8),  dim3(256), 0, stream, v, vT);
    hipLaunchKernelGGL(k_prep_w,dim3(7200),      dim3(256), 0, stream, w1, dw, w2, w1r, wdr, w2r);
    hipLaunchKernelGGL(k_pads,  dim3(1),         dim3(256), 0, stream, qkT);
    hipLaunchKernelGGL(k_conv1, dim3(144, 2, 3), dim3(256), 0, stream, qkT, w1r, feat3);
    hipLaunchKernelGGL(k_fcast, dim3(2305, 2),   dim3(256), 0, stream, feat3, b1, featb);
    hipLaunchKernelGGL(k_conv2, dim3(36, 2, 9),  dim3(256), 0, stream, featb, w2r, off9);
    hipLaunchKernelGGL(k_osum,  dim3(324),       dim3(256), 0, stream, off9, b2, off);
    hipLaunchKernelGGL(k_deform,dim3(576),       dim3(256), 0, stream, vT, off, wdr, db, q, out, p1);
    hipLaunchKernelGGL(k_dsum,  dim3(4608),      dim3(256), 0, stream, out, p1);
}

// Round 11
// 319.587 us; speedup vs baseline: 1.0733x; 1.0733x over previous
//
#include <hip/hip_runtime.h>
#include <string.h>

// Problem constants: B=2, obj=4, C=256, H=W=48, N=8, HW=2304
#define HH 48
#define WW 48
#define HWP 2304
#define CC 256
#define NB 8
#define QKROW 2305   // 2304 rows + 1 zero pad row (index 2304) for OOB taps

typedef __attribute__((ext_vector_type(8))) short short8;   // 8 x bf16 = 4 VGPR
typedef __attribute__((ext_vector_type(4))) float floatx4;  // MFMA C/D frag

static __device__ __forceinline__ unsigned short f2bf(float f) {
    union { float f; unsigned u; } v; v.f = f;
    unsigned r = v.u + 0x7fffu + ((v.u >> 16) & 1u);        // RNE
    return (unsigned short)(r >> 16);
}
static __device__ __forceinline__ float bflo(unsigned u) {
    union { unsigned u; float f; } x; x.u = u << 16; return x.f;
}
static __device__ __forceinline__ float bfhi(unsigned u) {
    union { unsigned u; float f; } x; x.u = u & 0xffff0000u; return x.f;
}
static __device__ __forceinline__ unsigned fbits(float f) {
    union { float f; unsigned u; } x; x.f = f; return x.u;
}
// combine one dword (2 bf16) of 4 corners -> packed bf16 pair
static __device__ __forceinline__ unsigned pk2(float w0, float w1, float w2, float w3,
        unsigned a, unsigned b, unsigned c, unsigned d) {
    float slo = w0 * bflo(a) + w1 * bflo(b) + w2 * bflo(c) + w3 * bflo(d);
    float shi = w0 * bfhi(a) + w1 * bfhi(b) + w2 * bfhi(c) + w3 * bfhi(d);
    return __builtin_amdgcn_perm(fbits(shi) + 0x8000u, fbits(slo) + 0x8000u, 0x07060302);
}

// ---- tiled transpose q/k -> qkT[b][px][c2] bf16 (64x64 tiles via LDS) ------
__global__ __launch_bounds__(256) void k_tr_qk(const float* __restrict__ q,
        const float* __restrict__ kk, unsigned short* __restrict__ qkT) {
    __shared__ float T[64][65];
    const int pg = blockIdx.x, cg = blockIdx.y;
    const int b = blockIdx.z >> 1, src = blockIdx.z & 1;
    const float* s = (src ? kk : q) + (size_t)b * CC * HWP;
    const int tx = threadIdx.x & 63, ty = threadIdx.x >> 6;
#pragma unroll
    for (int i = 0; i < 16; i++) {
        int cl = ty * 16 + i;
        T[cl][tx] = s[(size_t)(cg * 64 + cl) * HWP + pg * 64 + tx];
    }
    __syncthreads();
#pragma unroll
    for (int i = 0; i < 16; i++) {
        int pxl = ty * 16 + i;
        qkT[((size_t)b * QKROW + pg * 64 + pxl) * 512 + src * 256 + cg * 64 + tx]
            = f2bf(T[tx][pxl]);
    }
}

// ---- tiled transpose value -> vT[n][px][c] bf16 ----------------------------
__global__ __launch_bounds__(256) void k_tr_v(const float* __restrict__ v,
                                              unsigned short* __restrict__ vT) {
    __shared__ float T[64][65];
    const int pg = blockIdx.x, cg = blockIdx.y, n = blockIdx.z;
    const float* s = v + (size_t)n * CC * HWP;
    const int tx = threadIdx.x & 63, ty = threadIdx.x >> 6;
#pragma unroll
    for (int i = 0; i < 16; i++) {
        int cl = ty * 16 + i;
        T[cl][tx] = s[(size_t)(cg * 64 + cl) * HWP + pg * 64 + tx];
    }
    __syncthreads();
#pragma unroll
    for (int i = 0; i < 16; i++) {
        int pxl = ty * 16 + i;
        vT[((size_t)n * HWP + pg * 64 + pxl) * 256 + cg * 64 + tx] = f2bf(T[tx][pxl]);
    }
}

// ---- weight preshuffle into MFMA-fragment order (1KB contiguous frags) -----
__global__ __launch_bounds__(256) void k_prep_w(const float* __restrict__ w1,
        const float* __restrict__ dw, const float* __restrict__ w2,
        unsigned short* __restrict__ w1r, unsigned short* __restrict__ wdr,
        unsigned short* __restrict__ w2r) {
    int idx = blockIdx.x * 256 + threadIdx.x;
    if (idx < 1179648) {
        int j = idx & 7, l = (idx >> 3) & 63, mtg = (idx >> 9) & 15;
        int kk = (idx >> 13) & 15, tap = idx >> 17;
        int o = mtg * 16 + (l & 15);
        int c2 = kk * 32 + (l >> 4) * 8 + j;
        w1r[idx] = f2bf(w1[((size_t)o * 512 + c2) * 9 + tap]);
    } else if (idx < 1179648 + 589824) {
        int i2 = idx - 1179648;
        int j = i2 & 7, l = (i2 >> 3) & 63, mtg = (i2 >> 9) & 15;
        int kk = (i2 >> 13) & 7, tap = i2 >> 16;
        int o = mtg * 16 + (l & 15);
        int c = kk * 32 + (l >> 4) * 8 + j;
        wdr[i2] = f2bf(dw[((size_t)o * 256 + c) * 9 + tap]);
    } else {
        int i2 = idx - 1179648 - 589824;
        int j = i2 & 7, l = (i2 >> 3) & 63, mt = (i2 >> 9) & 1;
        int kk = (i2 >> 10) & 7, tap = i2 >> 13;
        int o = mt * 16 + (l & 15);
        int c = kk * 32 + (l >> 4) * 8 + j;
        w2r[i2] = (o < 18) ? f2bf(w2[((size_t)o * 256 + c) * 9 + tap]) : 0;
    }
}

// ---- zero qkT pad rows ------------------------------------------------------
__global__ __launch_bounds__(256) void k_pads(unsigned short* __restrict__ qkT) {
    int t = threadIdx.x;
#pragma unroll
    for (int b = 0; b < 2; b++) {
        qkT[((size_t)b * QKROW + HWP) * 512 + t] = 0;
        qkT[((size_t)b * QKROW + HWP) * 512 + 256 + t] = 0;
    }
}

// ---- conv1: 64px, tap-split(9) -> fp32 partials feat9[t][b][px][o] ---------
// grid (36, 2, 9). 4 waves x (64o x 64px), K=512 per block (one tap).
__global__ __launch_bounds__(256) void k_conv1(const unsigned short* __restrict__ qkT,
        const unsigned short* __restrict__ w1r, float* __restrict__ feat9) {
    const int tid = threadIdx.x;
    const int pb = blockIdx.x;            // 36
    const int b  = blockIdx.y;
    const int tap = blockIdx.z;           // 9
    const int lane = tid & 63, wv = tid >> 6;
    const int lo = lane & 15, quad = lane >> 4;
    const int dy = tap / 3 - 1, dx = tap % 3 - 1;

    size_t broff[4];
#pragma unroll
    for (int nt = 0; nt < 4; nt++) {
        int pp = pb * 64 + nt * 16 + lo;
        int h = pp / WW, w = pp - (pp / WW) * WW;
        bool val = (h + dy >= 0) && (h + dy < HH) && (w + dx >= 0) && (w + dx < WW);
        int row = val ? (pp + dy * WW + dx) : HWP;
        broff[nt] = ((size_t)b * QKROW + row) * 512 + quad * 8;
    }

    floatx4 acc[4][4];
#pragma unroll
    for (int mt = 0; mt < 4; mt++)
#pragma unroll
        for (int nt = 0; nt < 4; nt++) acc[mt][nt] = (floatx4)0.f;

    const unsigned short* afr = w1r + (((size_t)tap * 256 + wv * 4) * 64 + lane) * 8;
#pragma unroll 4
    for (int ks = 0; ks < 16; ks++) {
        const unsigned short* ak = afr + (size_t)ks * 16 * 512;
        short8 a0 = *(const short8*)(ak);
        short8 a1 = *(const short8*)(ak + 512);
        short8 a2 = *(const short8*)(ak + 1024);
        short8 a3 = *(const short8*)(ak + 1536);
        short8 bf[4];
#pragma unroll
        for (int nt = 0; nt < 4; nt++)
            bf[nt] = *(const short8*)(qkT + broff[nt] + ks * 32);
#pragma unroll
        for (int nt = 0; nt < 4; nt++) {
            acc[0][nt] = __builtin_amdgcn_mfma_f32_16x16x32_bf16(a0, bf[nt], acc[0][nt], 0, 0, 0);
            acc[1][nt] = __builtin_amdgcn_mfma_f32_16x16x32_bf16(a1, bf[nt], acc[1][nt], 0, 0, 0);
            acc[2][nt] = __builtin_amdgcn_mfma_f32_16x16x32_bf16(a2, bf[nt], acc[2][nt], 0, 0, 0);
            acc[3][nt] = __builtin_amdgcn_mfma_f32_16x16x32_bf16(a3, bf[nt], acc[3][nt], 0, 0, 0);
        }
    }

#pragma unroll
    for (int mt = 0; mt < 4; mt++) {
        int o = wv * 64 + mt * 16 + quad * 4;
#pragma unroll
        for (int nt = 0; nt < 4; nt++) {
            int pq = pb * 64 + nt * 16 + lo;
            *(floatx4*)(feat9 + (((size_t)tap * 2 + b) * HWP + pq) * 256 + o) = acc[mt][nt];
        }
    }
}

// ---- fcast: featb[b][px][o] = bf16(sum_t feat9 + b1), pad row zero ---------
__global__ __launch_bounds__(256) void k_fcast(const float* __restrict__ feat9,
        const float* __restrict__ b1, unsigned short* __restrict__ featb) {
    const int row = blockIdx.x;           // 0..2304
    const int b = blockIdx.y;
    const int c = threadIdx.x;
    size_t oidx = ((size_t)b * QKROW + row) * 256 + c;
    if (row < HWP) {
        float s = b1[c];
#pragma unroll
        for (int t = 0; t < 9; t++)
            s += feat9[(((size_t)t * 2 + b) * HWP + row) * 256 + c];
        featb[oidx] = f2bf(s);
    } else {
        featb[oidx] = 0;
    }
}

// ---- conv2: tap-split(9) -> fp32 partials off9[t][b][px][32] ---------------
__global__ __launch_bounds__(256) void k_conv2(const unsigned short* __restrict__ featb,
        const unsigned short* __restrict__ w2r, float* __restrict__ off9) {
    const int tid = threadIdx.x;
    const int pb = blockIdx.x;            // 36
    const int b  = blockIdx.y;
    const int tap = blockIdx.z;
    const int lane = tid & 63, wv = tid >> 6;
    const int lo = lane & 15, quad = lane >> 4;
    const int pp = pb * 64 + wv * 16 + lo;
    const int h = pp / WW, w = pp - (pp / WW) * WW;
    const int dy = tap / 3 - 1, dx = tap % 3 - 1;
    const bool val = (h + dy >= 0) && (h + dy < HH) && (w + dx >= 0) && (w + dx < WW);
    const int row = val ? (pp + dy * WW + dx) : HWP;

    const unsigned short* brow = featb + ((size_t)b * QKROW + row) * 256 + quad * 8;
    const unsigned short* afr = w2r + (((size_t)tap * 8 * 2) * 64 + lane) * 8;

    floatx4 acc[2];
    acc[0] = (floatx4)0.f; acc[1] = (floatx4)0.f;
#pragma unroll
    for (int ks = 0; ks < 8; ks++) {
        short8 bf = *(const short8*)(brow + ks * 32);
        const unsigned short* ak = afr + (size_t)ks * 2 * 512;
        short8 a0 = *(const short8*)(ak);
        short8 a1 = *(const short8*)(ak + 512);
        acc[0] = __builtin_amdgcn_mfma_f32_16x16x32_bf16(a0, bf, acc[0], 0, 0, 0);
        acc[1] = __builtin_amdgcn_mfma_f32_16x16x32_bf16(a1, bf, acc[1], 0, 0, 0);
    }

    float* dst = off9 + (((size_t)tap * 2 + b) * HWP + pp) * 32;
#pragma unroll
    for (int mt = 0; mt < 2; mt++) {
        int o = mt * 16 + quad * 4;
        *(floatx4*)(dst + o) = acc[mt];
    }
}

// ---- osum: off[b][o][px] = sum_t off9 + b2[o]  (o<18) ----------------------
__global__ __launch_bounds__(256) void k_osum(const float* __restrict__ off9,
        const float* __restrict__ b2, float* __restrict__ off) {
    int i = blockIdx.x * 256 + threadIdx.x;        // < 2*18*2304
    int b = i / (18 * HWP);
    int r = i - b * 18 * HWP;
    int o = r / HWP, px = r - o * HWP;
    float s = b2[o];
#pragma unroll
    for (int t = 0; t < 9; t++)
        s += off9[(((size_t)t * 2 + b) * HWP + px) * 32 + o];
    off[i] = s;
}

// ---- deform body: 64px block, segment-per-lane staging (8 lines/instr) -----
// Staging: lane covers 16B segment s=lane&31 of pixel pxl = wv*16+r*2+(lane>>5);
// 8 rounds x 4 corner loads stage 16 px/wave. Bilinear math replicated per
// 32-lane pixel group (cheap VALU); P footprint = 16 VGPRs.
// GEMM: 4 waves x (64o x 64px), acc 4x4, LDS 32 KB, R8 granule swizzle.
template<int TAP0, int NT, bool EPI>
__device__ __forceinline__ void deform_body(unsigned short* Sl,
        const unsigned short* __restrict__ vTn, const float* __restrict__ off,
        const unsigned short* __restrict__ wdr, const float* __restrict__ db,
        const float* __restrict__ q, float* __restrict__ dst,
        int b, int pb, int n, int tid) {
    const int lane = tid & 63, wv = tid >> 6;
    const int lo = lane & 15, quad = lane >> 4;
    const int s   = lane & 31;            // 16B segment within 512B row
    const int sub = lane >> 5;            // pixel parity within pair

    floatx4 acc[4][4];
#pragma unroll
    for (int mt = 0; mt < 4; mt++)
#pragma unroll
        for (int nt = 0; nt < 4; nt++) acc[mt][nt] = (floatx4)0.f;

#pragma unroll
    for (int i = 0; i < NT; i++) {
        const int tap = TAP0 + i;

        // ---- stage 16 px per wave: 8 rounds of 2 px ----
#pragma unroll 2
        for (int r = 0; r < 8; r++) {
            const int pxl = wv * 16 + r * 2 + sub;
            const int pp = pb * 64 + pxl;
            const int h = pp / WW, w = pp - (pp / WW) * WW;
            float dy = off[((size_t)b * 18 + 2 * tap) * HWP + pp];
            float dx = off[((size_t)b * 18 + 2 * tap + 1) * HWP + pp];
            float py = dy + (float)h + (float)(tap / 3 - 1);
            float px = dx + (float)w + (float)(tap % 3 - 1);
            float y0f = floorf(py), x0f = floorf(px);
            int y0 = (int)y0f, x0 = (int)x0f;
            float fy = py - y0f, fx = px - x0f;
            bool y0ok = (y0 >= 0) & (y0 < HH), y1ok = (y0 >= -1) & (y0 < HH - 1);
            bool x0ok = (x0 >= 0) & (x0 < WW), x1ok = (x0 >= -1) & (x0 < WW - 1);
            int y0c = min(max(y0, 0), HH - 1), y1c = min(max(y0 + 1, 0), HH - 1);
            int x0c = min(max(x0, 0), WW - 1), x1c = min(max(x0 + 1, 0), WW - 1);
            float w0 = (y0ok && x0ok) ? (1.f - fy) * (1.f - fx) : 0.f;
            float w1 = (y0ok && x1ok) ? (1.f - fy) * fx         : 0.f;
            float w2 = (y1ok && x0ok) ? fy * (1.f - fx)         : 0.f;
            float w3 = (y1ok && x1ok) ? fy * fx                 : 0.f;
            // lane reads its 16B segment of each corner row (8 lines/instr)
            uint4 c0 = *(const uint4*)(vTn + (size_t)(y0c * WW + x0c) * 256 + s * 8);
            uint4 c1 = *(const uint4*)(vTn + (size_t)(y0c * WW + x1c) * 256 + s * 8);
            uint4 c2 = *(const uint4*)(vTn + (size_t)(y1c * WW + x0c) * 256 + s * 8);
            uint4 c3 = *(const uint4*)(vTn + (size_t)(y1c * WW + x1c) * 256 + s * 8);
            uint4 od;
            od.x = pk2(w0, w1, w2, w3, c0.x, c1.x, c2.x, c3.x);
            od.y = pk2(w0, w1, w2, w3, c0.y, c1.y, c2.y, c3.y);
            od.z = pk2(w0, w1, w2, w3, c0.z, c1.z, c2.z, c3.z);
            od.w = pk2(w0, w1, w2, w3, c0.w, c1.w, c2.w, c3.w);
            int phys = s ^ (pxl & 7);                   // XOR-swizzled 16B granules
            *(uint4*)(Sl + (size_t)pxl * 256 + phys * 8) = od;
        }
        __syncthreads();

        // ---- GEMM over this tap (K=256) ----
        const unsigned short* afr = wdr + (((size_t)tap * 128 + wv * 4) * 64 + lane) * 8;
#pragma unroll
        for (int ks = 0; ks < 8; ks++) {
            const unsigned short* ak = afr + (size_t)ks * 16 * 512;
            short8 a0 = *(const short8*)(ak);
            short8 a1 = *(const short8*)(ak + 512);
            short8 a2 = *(const short8*)(ak + 1024);
            short8 a3 = *(const short8*)(ak + 1536);
            short8 bf[4];
#pragma unroll
            for (int nt = 0; nt < 4; nt++) {
                int rw = nt * 16 + lo;
                int gr = (ks * 4 + quad) ^ (rw & 7);
                bf[nt] = *(const short8*)(Sl + (size_t)rw * 256 + gr * 8);
            }
#pragma unroll
            for (int nt = 0; nt < 4; nt++) {
                acc[0][nt] = __builtin_amdgcn_mfma_f32_16x16x32_bf16(a0, bf[nt], acc[0][nt], 0, 0, 0);
                acc[1][nt] = __builtin_amdgcn_mfma_f32_16x16x32_bf16(a1, bf[nt], acc[1][nt], 0, 0, 0);
                acc[2][nt] = __builtin_amdgcn_mfma_f32_16x16x32_bf16(a2, bf[nt], acc[2][nt], 0, 0, 0);
                acc[3][nt] = __builtin_amdgcn_mfma_f32_16x16x32_bf16(a3, bf[nt], acc[3][nt], 0, 0, 0);
            }
        }
        __syncthreads();
    }

    // epilogue
#pragma unroll
    for (int mt = 0; mt < 4; mt++) {
        int o = wv * 64 + mt * 16 + quad * 4;
#pragma unroll
        for (int nt = 0; nt < 4; nt++) {
            int pq = pb * 64 + nt * 16 + lo;
            floatx4 r = acc[mt][nt];
            if (EPI) {
                r[0] += db[o]     + q[((size_t)b * CC + o + 0) * HWP + pq];
                r[1] += db[o + 1] + q[((size_t)b * CC + o + 1) * HWP + pq];
                r[2] += db[o + 2] + q[((size_t)b * CC + o + 2) * HWP + pq];
                r[3] += db[o + 3] + q[((size_t)b * CC + o + 3) * HWP + pq];
            }
            *(floatx4*)(dst + ((size_t)pq * NB + n) * CC + o) = r;
        }
    }
}

// ---- deform: 64px blocks, 2-way tap split, XCD-swizzled --------------------
// grid 576: n = bid&7, r = bid>>3 (72): pb = r%36, g = r/36.
// g0: taps 0-3 + (q+db) epilogue -> out ; g1: taps 4-8 -> p1 (k_dsum adds).
__global__ __launch_bounds__(256) void k_deform(const unsigned short* __restrict__ vT,
        const float* __restrict__ off, const unsigned short* __restrict__ wdr,
        const float* __restrict__ db, const float* __restrict__ q,
        float* __restrict__ out, float* __restrict__ p1) {
    __shared__ __align__(16) unsigned short Sl[64 * 256];   // 32 KB

    const int tid = threadIdx.x;
    const int bid = blockIdx.x;           // 576
    const int n   = bid & 7;              // XCD swizzle: same n -> same XCD
    const int r   = bid >> 3;             // 72
    const int pb  = r % 36;
    const int g   = r / 36;               // 0 or 1
    const int b   = n >> 2;
    const unsigned short* vTn = vT + (size_t)n * HWP * 256;

    if (g == 0)
        deform_body<0, 4, true >(Sl, vTn, off, wdr, db, q, out, b, pb, n, tid);
    else
        deform_body<4, 5, false>(Sl, vTn, off, wdr, db, q, p1,  b, pb, n, tid);
}

// ---- dsum: out += p1 (coalesced float4) ------------------------------------
__global__ __launch_bounds__(256) void k_dsum(float* __restrict__ out,
                                              const float* __restrict__ p1) {
    int i = blockIdx.x * 256 + threadIdx.x;        // 1,179,648 float4s
    float4 a = ((const float4*)out)[i];
    float4 c = ((const float4*)p1)[i];
    a.x += c.x; a.y += c.y; a.z += c.z; a.w += c.w;
    ((float4*)out)[i] = a;
}

extern "C" void kernel_launch(void* const* d_in, const int* in_sizes, int n_in,
                              void* d_out, int out_size, void* d_ws, size_t ws_size,
                              hipStream_t stream) {
    const float* q  = (const float*)d_in[0];
    const float* k  = (const float*)d_in[1];
    const float* v  = (const float*)d_in[2];
    const float* w1 = (const float*)d_in[3];
    const float* b1 = (const float*)d_in[4];
    const float* w2 = (const float*)d_in[5];
    const float* b2 = (const float*)d_in[6];
    const float* dw = (const float*)d_in[7];
    const float* db = (const float*)d_in[8];
    float* out = (float*)d_out;

    // ws (~63 MB): off | X (feat9, later aliased by off9+p1) || bf16 buffers.
    // Aliasing is stream-ordered: feat9 fully consumed by k_fcast before
    // k_conv2 writes off9 / k_deform writes p1 into the same region.
    float* off   = (float*)d_ws;                          //    82,944 f
    float* X     = off + 82944;                           // 10,616,832 f
    float* feat9 = X;                                     // 9*2*2304*256
    float* off9  = X;                                     // 1,327,104 (alias)
    float* p1    = X + 1327104;                           // 4,718,592 (alias)
    unsigned short* qkT   = (unsigned short*)(X + 10616832);
    unsigned short* vT    = qkT + 2360320;                // 2*2305*512
    unsigned short* featb = vT + 4718592;                 // 8*2304*256
    unsigned short* w1r   = featb + 1180160;              // 2*2305*256
    unsigned short* wdr   = w1r + 1179648;                // 256*4608 (frag order)
    unsigned short* w2r   = wdr + 589824;                 // 256*2304 (frag order)

    hipLaunchKernelGGL(k_tr_qk, dim3(36, 4, 4), dim3(256), 0, stream, q, k, qkT);
    hipLaunchKernelGGL(k_tr_v,  dim3(36, 4, 8), dim3(256), 0, stream, v, vT);
    hipLaunchKernelGGL(k_prep_w,dim3(7200),     dim3(256), 0, stream, w1, dw, w2, w1r, wdr, w2r);
    hipLaunchKernelGGL(k_pads,  dim3(1),        dim3(256), 0, stream, qkT);
    hipLaunchKernelGGL(k_conv1, dim3(36, 2, 9), dim3(256), 0, stream, qkT, w1r, feat9);
    hipLaunchKernelGGL(k_fcast, dim3(2305, 2),  dim3(256), 0, stream, feat9, b1, featb);
    hipLaunchKernelGGL(k_conv2, dim3(36, 2, 9), dim3(256), 0, stream, featb, w2r, off9);
    hipLaunchKernelGGL(k_osum,  dim3(324),      dim3(256), 0, stream, off9, b2, off);
    hipLaunchKernelGGL(k_deform,dim3(576),      dim3(256), 0, stream, vT, off, wdr, db, q, out, p1);
    hipLaunchKernelGGL(k_dsum,  dim3(4608),     dim3(256), 0, stream, out, p1);
}